// Round 2
// baseline (78.575 us; speedup 1.0000x reference)
//
#include <hip/hip_runtime.h>

// y[b,o] = sum_i x[b,i] * (wp[i,o] - wn[i,o]) + (bp[o] - bn[o])
// (G_OFF / k_cond / K_V cancel exactly in the differential-pair readout)
//
// v2 re-run (round-1 failure was container/infra, no dispatch reached HW).
//  - x staged TRANSPOSED in LDS (xs[k][b], stride 132) -> x fragment is 2x ds_read_b128
//  - 8b x 8o micro-tile: 4 ds_read_b128 per 64 FMA (was 9 LDS instrs per 32 FMA)
//  - KC=32 / NKS=32 keeps 512 blocks x 2 waves = 1024 waves (1 per SIMD)
//  - reduce: 128 blocks, 4 outs/thread, coalesced 8B slice loads
// bf16 partials: 32 slices, ~4e-4 RNE err/slice, random-walk ~4e-3 total;
// threshold 0.154 (prev absmax 0.031 at 16 slices).

#define NB   128
#define NIN  1024
#define NOUT 1024

#define OT   64              // output cols per block
#define KC   32              // k-chunk per block
#define NKS  (NIN / KC)      // 32 K-split slices
#define XS   132             // xs row stride (floats): rows 16B-aligned, writes <=4-way alias
#define WDS  68              // wd row stride (floats): rows 16B-aligned

__device__ __forceinline__ unsigned short f32_to_bf16_rne(float f) {
    union { float f; unsigned u; } c; c.f = f;
    unsigned u = c.u + 0x7FFFu + ((c.u >> 16) & 1u);   // round-to-nearest-even
    return (unsigned short)(u >> 16);
}
__device__ __forceinline__ float bf16_to_f32(unsigned short h) {
    union { unsigned u; float f; } c; c.u = ((unsigned)h) << 16;
    return c.f;
}

__global__ __launch_bounds__(128) void memr_partial(
    const float* __restrict__ x,  const float* __restrict__ wp,
    const float* __restrict__ wn, unsigned short* __restrict__ ws)
{
    __shared__ float xs[KC * XS];   // 16896 B : x^T   [kk][b]   (transposed!)
    __shared__ float wd[KC * WDS];  //  8704 B : wp-wn [kk][o]

    const int t  = threadIdx.x;
    const int o0 = blockIdx.x * OT;
    const int ks = blockIdx.y;
    const int k0 = ks * KC;

    // ---- stage x^T: 1024 coalesced float4 global reads, transposed scalar LDS writes
    #pragma unroll
    for (int r = 0; r < 8; ++r) {
        const int f4 = r * 128 + t;
        const int b  = f4 >> 3;            // 8 float4 per 32-float k-row
        const int q  = f4 & 7;
        const float4 v = *(const float4*)&x[(size_t)b * NIN + k0 + q * 4];
        xs[(q * 4 + 0) * XS + b] = v.x;
        xs[(q * 4 + 1) * XS + b] = v.y;
        xs[(q * 4 + 2) * XS + b] = v.z;
        xs[(q * 4 + 3) * XS + b] = v.w;
    }
    // ---- stage wd = wp - wn : 512 float4 each, coalesced
    #pragma unroll
    for (int r = 0; r < 4; ++r) {
        const int f4 = r * 128 + t;
        const int kk = f4 >> 4;            // 16 float4 per 64-float o-row
        const int q  = f4 & 15;
        const size_t g = (size_t)(k0 + kk) * NOUT + o0 + q * 4;
        const float4 p = *(const float4*)&wp[g];
        const float4 n = *(const float4*)&wn[g];
        float4 d;
        d.x = p.x - n.x; d.y = p.y - n.y; d.z = p.z - n.z; d.w = p.w - n.w;
        *(float4*)&wd[kk * WDS + q * 4] = d;
    }
    __syncthreads();

    // micro-tile: 8 batch rows x 8 output cols per thread (64 acc VGPRs)
    const int to = t & 7;    // o-octet: o = o0 + to*8 + j
    const int tb = t >> 3;   // b-octet: b = tb*8 + i

    float acc[8][8];
    #pragma unroll
    for (int i = 0; i < 8; ++i)
        #pragma unroll
        for (int j = 0; j < 8; ++j) acc[i][j] = 0.f;

    const float* xr = &xs[tb * 8];
    const float* wr = &wd[to * 8];

    #pragma unroll 4
    for (int kk = 0; kk < KC; ++kk) {
        const float4 xa = *(const float4*)&xr[kk * XS];
        const float4 xb = *(const float4*)&xr[kk * XS + 4];
        const float4 wa = *(const float4*)&wr[kk * WDS];
        const float4 wb = *(const float4*)&wr[kk * WDS + 4];
        const float xv[8] = {xa.x, xa.y, xa.z, xa.w, xb.x, xb.y, xb.z, xb.w};
        const float wv[8] = {wa.x, wa.y, wa.z, wa.w, wb.x, wb.y, wb.z, wb.w};
        #pragma unroll
        for (int i = 0; i < 8; ++i)
            #pragma unroll
            for (int j = 0; j < 8; ++j)
                acc[i][j] += xv[i] * wv[j];
    }

    // ---- store 8x8 partial tile to ws[ks][b][o] as bf16 (2x 8B stores/row, coalesced)
    unsigned short* wsb = ws + (size_t)ks * NB * NOUT + o0 + to * 8;
    #pragma unroll
    for (int i = 0; i < 8; ++i) {
        const int b = tb * 8 + i;
        ushort4 v0, v1;
        v0.x = f32_to_bf16_rne(acc[i][0]); v0.y = f32_to_bf16_rne(acc[i][1]);
        v0.z = f32_to_bf16_rne(acc[i][2]); v0.w = f32_to_bf16_rne(acc[i][3]);
        v1.x = f32_to_bf16_rne(acc[i][4]); v1.y = f32_to_bf16_rne(acc[i][5]);
        v1.z = f32_to_bf16_rne(acc[i][6]); v1.w = f32_to_bf16_rne(acc[i][7]);
        *(ushort4*)&wsb[(size_t)b * NOUT]     = v0;
        *(ushort4*)&wsb[(size_t)b * NOUT + 4] = v1;
    }
}

__global__ __launch_bounds__(256) void memr_reduce(
    const unsigned short* __restrict__ ws, const float* __restrict__ bp,
    const float* __restrict__ bn, float* __restrict__ out)
{
    // 4 outputs per thread: 8B bf16x4 load per slice (coalesced 512B/wave), fp32 accum
    const int g  = blockIdx.x * 256 + threadIdx.x;  // 0..32767
    const int i4 = g * 4;
    const int o4 = i4 & (NOUT - 1);

    const float4 bpv = *(const float4*)&bp[o4];
    const float4 bnv = *(const float4*)&bn[o4];
    float s0 = bpv.x - bnv.x, s1 = bpv.y - bnv.y;
    float s2 = bpv.z - bnv.z, s3 = bpv.w - bnv.w;

    #pragma unroll
    for (int ks = 0; ks < NKS; ++ks) {
        const ushort4 u = *(const ushort4*)&ws[(size_t)ks * NB * NOUT + i4];
        s0 += bf16_to_f32(u.x); s1 += bf16_to_f32(u.y);
        s2 += bf16_to_f32(u.z); s3 += bf16_to_f32(u.w);
    }
    float4 o; o.x = s0; o.y = s1; o.z = s2; o.w = s3;
    *(float4*)&out[i4] = o;
}

extern "C" void kernel_launch(void* const* d_in, const int* in_sizes, int n_in,
                              void* d_out, int out_size, void* d_ws, size_t ws_size,
                              hipStream_t stream)
{
    const float* x  = (const float*)d_in[0];
    const float* wp = (const float*)d_in[1];
    const float* wn = (const float*)d_in[2];
    const float* bp = (const float*)d_in[3];
    const float* bn = (const float*)d_in[4];
    float* out = (float*)d_out;
    unsigned short* ws = (unsigned short*)d_ws;   // 32*128*1024*2 = 8 MB used

    dim3 g1(NOUT / OT, NKS);       // 16 x 32 = 512 blocks, 2 per CU
    memr_partial<<<g1, 128, 0, stream>>>(x, wp, wn, ws);
    memr_reduce<<<NB * NOUT / 4 / 256, 256, 0, stream>>>(ws, bp, bn, out);
}